// Round 1
// baseline (398.341 us; speedup 1.0000x reference)
//
#include <hip/hip_runtime.h>
#include <hip/hip_bf16.h>

// ---------------- problem constants (fixed by setup_inputs) ----------------
constexpr int B_  = 8;
constexpr int H_  = 64;
constexpr int W_  = 64;
constexpr int C_  = 192;
constexpr int Dn  = 192;
constexpr int Nst = 8;    // state dim N
constexpr int R_  = 12;
constexpr int K_  = 4;    // directions
constexpr int L_  = H_ * W_;          // 4096
constexpr int CS  = 64;               // scan chunk size
constexpr int NC  = L_ / CS;          // 64 chunks
constexpr int CPROJ = R_ + 2 * Nst;   // 28 proj outputs per direction
constexpr int MROWS = B_ * L_;        // 32768

// t -> spatial row permutation for direction k (input gather AND output scatter
// use the same map; verified: transpose is (l%64)*64 + l/64, flip is L-1-l)
__device__ __forceinline__ int map_t(int k, int t) {
    int tt = (k >= 2) ? (L_ - 1 - t) : t;
    if (k & 1) tt = (tt & 63) * 64 + (tt >> 6);
    return tt;
}

__device__ __forceinline__ float softplus_f(float x) {
    return (x > 20.f) ? x : __logf(1.f + __expf(x));
}

// ---------------- generic f32 GEMM: C[m,n] = sum_k A[m,k] * W[n,k] ----------
// BM=BN=BK=64, 256 threads, 4x4 register tile per thread.
// EPI==0: write out0[m*N+n]. EPI==1: split (in_proj): n<192 -> out0, else out1.
template <int EPI>
__global__ __launch_bounds__(256) void k_gemm(const float* __restrict__ A,
                                              const float* __restrict__ Wt,
                                              float* __restrict__ out0,
                                              float* __restrict__ out1,
                                              int N, int K) {
    __shared__ float As[64][68];  // [kk][m], 68 pad: 16B aligned rows, no conflicts
    __shared__ float Bs[64][68];  // [kk][n]
    const int m0 = blockIdx.x * 64, n0 = blockIdx.y * 64;
    const int tid = threadIdx.x;
    const int tx = tid & 15, ty = tid >> 4;

    float acc[4][4] = {};
    for (int k0 = 0; k0 < K; k0 += 64) {
#pragma unroll
        for (int i = 0; i < 4; i++) {
            int f = tid + i * 256;          // 0..1023
            int r = f >> 4, cg = f & 15;    // row in tile, float4-group in k
            float4 v = *reinterpret_cast<const float4*>(A + (size_t)(m0 + r) * K + k0 + cg * 4);
            As[cg * 4 + 0][r] = v.x; As[cg * 4 + 1][r] = v.y;
            As[cg * 4 + 2][r] = v.z; As[cg * 4 + 3][r] = v.w;
            int wr = n0 + r;
            float4 u = make_float4(0.f, 0.f, 0.f, 0.f);
            if (wr < N) u = *reinterpret_cast<const float4*>(Wt + (size_t)wr * K + k0 + cg * 4);
            Bs[cg * 4 + 0][r] = u.x; Bs[cg * 4 + 1][r] = u.y;
            Bs[cg * 4 + 2][r] = u.z; Bs[cg * 4 + 3][r] = u.w;
        }
        __syncthreads();
#pragma unroll
        for (int kk = 0; kk < 64; kk++) {
            float4 av = *reinterpret_cast<const float4*>(&As[kk][ty * 4]);
            float4 bv = *reinterpret_cast<const float4*>(&Bs[kk][tx * 4]);
            float a[4] = {av.x, av.y, av.z, av.w};
            float b[4] = {bv.x, bv.y, bv.z, bv.w};
#pragma unroll
            for (int i = 0; i < 4; i++)
#pragma unroll
                for (int j = 0; j < 4; j++) acc[i][j] = fmaf(a[i], b[j], acc[i][j]);
        }
        __syncthreads();
    }
#pragma unroll
    for (int i = 0; i < 4; i++) {
        int m = m0 + ty * 4 + i;
#pragma unroll
        for (int j = 0; j < 4; j++) {
            int n = n0 + tx * 4 + j;
            if (EPI == 0) {
                if (n < N) out0[(size_t)m * N + n] = acc[i][j];
            } else {  // in_proj split: xf | z, each ldc=192
                if (n < 192) out0[(size_t)m * 192 + n] = acc[i][j];
                else         out1[(size_t)m * 192 + (n - 192)] = acc[i][j];
            }
        }
    }
}

// ---------------- depthwise 3x3 conv (NHWC over (B,L,Dn)) + bias + SiLU -----
__global__ __launch_bounds__(256) void k_conv(const float* __restrict__ xf,
                                              const float* __restrict__ cw,
                                              const float* __restrict__ cb,
                                              float* __restrict__ xc) {
    size_t i = (size_t)blockIdx.x * 256 + threadIdx.x;  // over B*H*W*Dn
    int d = (int)(i % Dn);
    int p = (int)(i / Dn);
    int w = p & 63; p >>= 6;
    int h = p & 63; p >>= 6;
    int b = p;
    float acc = cb[d];
#pragma unroll
    for (int kh = 0; kh < 3; kh++) {
        int hh = h + kh - 1;
        if (hh < 0 || hh >= H_) continue;
#pragma unroll
        for (int kw = 0; kw < 3; kw++) {
            int ww = w + kw - 1;
            if (ww < 0 || ww >= W_) continue;
            acc = fmaf(xf[(((size_t)b * H_ + hh) * W_ + ww) * Dn + d],
                       cw[d * 9 + kh * 3 + kw], acc);
        }
    }
    float sig = 1.f / (1.f + __expf(-acc));
    xc[i] = acc * sig;
}

// ---------------- scan phase 1: per-chunk (prod(a), h_partial) --------------
__global__ __launch_bounds__(192) void k_scan1(const float* __restrict__ xc,
                                               const float* __restrict__ xdbl,
                                               const float* __restrict__ dtw_all,
                                               const float* __restrict__ dtb_all,
                                               const float* __restrict__ alog,
                                               float* __restrict__ Aprod,
                                               float* __restrict__ hpart) {
    const int blk = blockIdx.x;            // ((b*K + k)*NC + c)
    const int c = blk % NC;
    const int k = (blk / NC) % K_;
    const int b = blk / (NC * K_);
    const int d = threadIdx.x;
    const int t0 = c * CS;

    __shared__ float sx[CS][CPROJ];        // dt_r(12) | B(8) | C(8) per step
    for (int i = d; i < CS * CPROJ; i += 192) {
        int ts = i / CPROJ, j = i % CPROJ;
        sx[ts][j] = xdbl[((size_t)b * L_ + map_t(k, t0 + ts)) * (K_ * CPROJ) + k * CPROJ + j];
    }
    __syncthreads();

    float dtw[R_];
#pragma unroll
    for (int r = 0; r < R_; r++) dtw[r] = dtw_all[((size_t)k * Dn + d) * R_ + r];
    const float bias = dtb_all[k * Dn + d];
    float Av[Nst];
#pragma unroll
    for (int n = 0; n < Nst; n++) Av[n] = -__expf(alog[((size_t)k * Dn + d) * Nst + n]);

    float h[Nst] = {}, Ap[Nst];
#pragma unroll
    for (int n = 0; n < Nst; n++) Ap[n] = 1.f;

    float u_next = xc[((size_t)b * L_ + map_t(k, t0)) * Dn + d];
    for (int ts = 0; ts < CS; ts++) {
        float u = u_next;
        if (ts + 1 < CS) u_next = xc[((size_t)b * L_ + map_t(k, t0 + ts + 1)) * Dn + d];
        float x = bias;
#pragma unroll
        for (int r = 0; r < R_; r++) x = fmaf(sx[ts][r], dtw[r], x);
        float delta = softplus_f(x);
        float du = delta * u;
#pragma unroll
        for (int n = 0; n < Nst; n++) {
            float a = __expf(delta * Av[n]);
            Ap[n] *= a;
            h[n] = fmaf(a, h[n], du * sx[ts][R_ + n]);
        }
    }
    size_t base = ((((size_t)(b * K_ + k) * NC + c) * Dn + d)) * Nst;
#pragma unroll
    for (int n = 0; n < Nst; n++) { Aprod[base + n] = Ap[n]; hpart[base + n] = h[n]; }
}

// ---------------- scan phase 2: chunk-level recurrence -----------------------
__global__ __launch_bounds__(256) void k_scan2(const float* __restrict__ Aprod,
                                               const float* __restrict__ hpart,
                                               float* __restrict__ hin) {
    int idx = blockIdx.x * 256 + threadIdx.x;   // B*K*Dn*Nst = 49152 exactly
    int dn = idx % (Dn * Nst);
    int bk = idx / (Dn * Nst);
    size_t stride = (size_t)Dn * Nst;
    size_t base = (size_t)bk * NC * stride + dn;
    float h = 0.f;
    for (int cc = 0; cc < NC; cc++) {
        size_t s = base + (size_t)cc * stride;
        hin[s] = h;
        h = fmaf(Aprod[s], h, hpart[s]);
    }
}

// ---------------- scan phase 3: recompute with h_in, emit y (scatter) -------
__global__ __launch_bounds__(192) void k_scan3(const float* __restrict__ xc,
                                               const float* __restrict__ xdbl,
                                               const float* __restrict__ dtw_all,
                                               const float* __restrict__ dtb_all,
                                               const float* __restrict__ alog,
                                               const float* __restrict__ dvec,
                                               const float* __restrict__ hin,
                                               float* __restrict__ ycomb) {
    const int blk = blockIdx.x;
    const int c = blk % NC;
    const int k = (blk / NC) % K_;
    const int b = blk / (NC * K_);
    const int d = threadIdx.x;
    const int t0 = c * CS;

    __shared__ float sx[CS][CPROJ];
    for (int i = d; i < CS * CPROJ; i += 192) {
        int ts = i / CPROJ, j = i % CPROJ;
        sx[ts][j] = xdbl[((size_t)b * L_ + map_t(k, t0 + ts)) * (K_ * CPROJ) + k * CPROJ + j];
    }
    __syncthreads();

    float dtw[R_];
#pragma unroll
    for (int r = 0; r < R_; r++) dtw[r] = dtw_all[((size_t)k * Dn + d) * R_ + r];
    const float bias = dtb_all[k * Dn + d];
    const float Dk = dvec[k * Dn + d];
    float Av[Nst];
#pragma unroll
    for (int n = 0; n < Nst; n++) Av[n] = -__expf(alog[((size_t)k * Dn + d) * Nst + n]);

    size_t base = ((((size_t)(b * K_ + k) * NC + c) * Dn + d)) * Nst;
    float h[Nst];
#pragma unroll
    for (int n = 0; n < Nst; n++) h[n] = hin[base + n];

    int lm = map_t(k, t0);
    float u_next = xc[((size_t)b * L_ + lm) * Dn + d];
    for (int ts = 0; ts < CS; ts++) {
        int lm_cur = lm;
        float u = u_next;
        if (ts + 1 < CS) {
            lm = map_t(k, t0 + ts + 1);
            u_next = xc[((size_t)b * L_ + lm) * Dn + d];
        }
        float x = bias;
#pragma unroll
        for (int r = 0; r < R_; r++) x = fmaf(sx[ts][r], dtw[r], x);
        float delta = softplus_f(x);
        float du = delta * u;
        float y = 0.f;
#pragma unroll
        for (int n = 0; n < Nst; n++) {
            float a = __expf(delta * Av[n]);
            h[n] = fmaf(a, h[n], du * sx[ts][R_ + n]);
            y = fmaf(h[n], sx[ts][R_ + Nst + n], y);
        }
        float outv = fmaf(Dk, u, y);
        atomicAdd(&ycomb[((size_t)b * L_ + lm_cur) * Dn + d], outv);
    }
}

// ---------------- combine output: LayerNorm(Dn) * SiLU(z) -------------------
__global__ __launch_bounds__(192) void k_ln(const float* __restrict__ ycomb,
                                            const float* __restrict__ zbuf,
                                            const float* __restrict__ lnw,
                                            const float* __restrict__ lnb,
                                            float* __restrict__ yfin) {
    const int bl = blockIdx.x;     // b*L + l
    const int d = threadIdx.x;
    float v = ycomb[(size_t)bl * Dn + d];
    float s = v, s2 = v * v;
#pragma unroll
    for (int o = 32; o > 0; o >>= 1) {
        s += __shfl_down(s, o);
        s2 += __shfl_down(s2, o);
    }
    __shared__ float red[6];
    int wv = d >> 6;
    if ((d & 63) == 0) { red[wv] = s; red[3 + wv] = s2; }
    __syncthreads();
    float sum = red[0] + red[1] + red[2];
    float sum2 = red[3] + red[4] + red[5];
    const float inv = 1.f / 192.f;
    float mu = sum * inv;
    float var = sum2 * inv - mu * mu;
    float rstd = rsqrtf(var + 1e-5f);
    float zz = zbuf[(size_t)bl * Dn + d];
    float sig = 1.f / (1.f + __expf(-zz));
    yfin[(size_t)bl * Dn + d] = ((v - mu) * rstd * lnw[d] + lnb[d]) * (zz * sig);
}

// ---------------- launcher ---------------------------------------------------
extern "C" void kernel_launch(void* const* d_in, const int* in_sizes, int n_in,
                              void* d_out, int out_size, void* d_ws, size_t ws_size,
                              hipStream_t stream) {
    const float* x    = (const float*)d_in[0];
    const float* w_in = (const float*)d_in[1];
    const float* cw   = (const float*)d_in[2];
    const float* cb   = (const float*)d_in[3];
    const float* xpw  = (const float*)d_in[4];   // (K,28,192) == (112,192)
    const float* dtw  = (const float*)d_in[5];
    const float* dtb  = (const float*)d_in[6];
    const float* alog = (const float*)d_in[7];
    const float* dvec = (const float*)d_in[8];
    const float* lnw  = (const float*)d_in[9];
    const float* lnb  = (const float*)d_in[10];
    const float* wout = (const float*)d_in[11];
    float* out = (float*)d_out;

    float* ws = (float*)d_ws;
    const size_t MBL = (size_t)MROWS * Dn;               // 6,291,456
    const size_t SCN = (size_t)B_ * K_ * NC * Dn * Nst;  // 3,145,728
    float* xf    = ws;
    float* z     = xf + MBL;
    float* xc    = z + MBL;
    float* xdbl  = xc + MBL;                  // (B*L, 112)
    float* Aprod = xdbl + (size_t)MROWS * (K_ * CPROJ);
    float* hpart = Aprod + SCN;
    float* hin   = hpart + SCN;
    float* ycomb = hin + SCN;                 // (B*L, Dn)
    float* yfin  = xf;                        // reuse xf after conv

    // zero the scatter accumulator (graph-capture-safe memset node)
    hipMemsetAsync(ycomb, 0, MBL * sizeof(float), stream);

    // 1. in_proj: xz = x @ W^T, split -> xf, z
    k_gemm<1><<<dim3(MROWS / 64, 6), 256, 0, stream>>>(x, w_in, xf, z, 2 * Dn, C_);
    // 2. depthwise conv 3x3 + bias + SiLU
    k_conv<<<(int)(MBL / 256), 256, 0, stream>>>(xf, cw, cb, xc);
    // 3. x_dbl for all 4 directions in one GEMM (permutation deferred to scan)
    k_gemm<0><<<dim3(MROWS / 64, 2), 256, 0, stream>>>(xc, xpw, xdbl, nullptr,
                                                       K_ * CPROJ, Dn);
    // 4-6. chunked parallel selective scan
    k_scan1<<<B_ * K_ * NC, 192, 0, stream>>>(xc, xdbl, dtw, dtb, alog, Aprod, hpart);
    k_scan2<<<(B_ * K_ * Dn * Nst) / 256, 256, 0, stream>>>(Aprod, hpart, hin);
    k_scan3<<<B_ * K_ * NC, 192, 0, stream>>>(xc, xdbl, dtw, dtb, alog, dvec, hin, ycomb);
    // 7. LayerNorm * SiLU(z)
    k_ln<<<MROWS, 192, 0, stream>>>(ycomb, z, lnw, lnb, yfin);
    // 8. out_proj -> d_out
    k_gemm<0><<<dim3(MROWS / 64, 3), 256, 0, stream>>>(yfin, wout, out, nullptr, C_, Dn);
}

// Round 2
// 308.401 us; speedup vs baseline: 1.2916x; 1.2916x over previous
//
#include <hip/hip_runtime.h>
#include <hip/hip_bf16.h>

// ---------------- problem constants (fixed by setup_inputs) ----------------
constexpr int B_  = 8;
constexpr int H_  = 64;
constexpr int W_  = 64;
constexpr int C_  = 192;
constexpr int Dn  = 192;
constexpr int Nst = 8;    // state dim N
constexpr int R_  = 12;
constexpr int K_  = 4;    // directions
constexpr int L_  = H_ * W_;          // 4096
constexpr int CS  = 64;               // scan chunk size
constexpr int NC  = L_ / CS;          // 64 chunks
constexpr int CPROJ = R_ + 2 * Nst;   // 28 proj outputs per direction
constexpr int MROWS = B_ * L_;        // 32768

typedef __attribute__((ext_vector_type(8))) short short8v;
typedef __attribute__((ext_vector_type(4))) float f32x4;

// t -> spatial position for direction k (gather map; verified in round 0)
__device__ __forceinline__ int map_t(int k, int t) {
    int tt = (k >= 2) ? (L_ - 1 - t) : t;
    if (k & 1) tt = (tt & 63) * 64 + (tt >> 6);
    return tt;
}

__device__ __forceinline__ float softplus_f(float x) {
    return (x > 20.f) ? x : __logf(1.f + __expf(x));
}

__device__ __forceinline__ short f2bf(float f) {   // round-to-nearest-even
    unsigned u = __float_as_uint(f);
    u += 0x7FFFu + ((u >> 16) & 1u);
    return (short)(u >> 16);
}

// ---------------- f32 -> bf16 converters ------------------------------------
__global__ __launch_bounds__(256) void k_cvt_x(const float* __restrict__ in,
                                               short* __restrict__ out) {
    size_t i = ((size_t)blockIdx.x * 256 + threadIdx.x) * 8;
    float4 a = *reinterpret_cast<const float4*>(in + i);
    float4 b = *reinterpret_cast<const float4*>(in + i + 4);
    short8v v = {f2bf(a.x), f2bf(a.y), f2bf(a.z), f2bf(a.w),
                 f2bf(b.x), f2bf(b.y), f2bf(b.z), f2bf(b.w)};
    *reinterpret_cast<short8v*>(out + i) = v;
}

// concat-convert the three weight matrices into one bf16 buffer
constexpr int WOFF_IN  = 0;               // w_in  (384x192) = 73728
constexpr int WOFF_XP  = 73728;           // xpw   (112x192) = 21504
constexpr int WOFF_OUT = 95232;           // wout  (192x192) = 36864
constexpr int WTOTAL   = 132096;
__global__ __launch_bounds__(256) void k_cvt_w(const float* __restrict__ w_in,
                                               const float* __restrict__ xpw,
                                               const float* __restrict__ wout,
                                               short* __restrict__ dst) {
    int base = (blockIdx.x * 256 + threadIdx.x) * 8;
    if (base >= WTOTAL) return;
    const float* src; int off;
    if (base < WOFF_XP)       { src = w_in; off = base; }
    else if (base < WOFF_OUT) { src = xpw;  off = base - WOFF_XP; }
    else                      { src = wout; off = base - WOFF_OUT; }
    float4 a = *reinterpret_cast<const float4*>(src + off);
    float4 b = *reinterpret_cast<const float4*>(src + off + 4);
    short8v v = {f2bf(a.x), f2bf(a.y), f2bf(a.z), f2bf(a.w),
                 f2bf(b.x), f2bf(b.y), f2bf(b.z), f2bf(b.w)};
    *reinterpret_cast<short8v*>(dst + base) = v;
}

// ---------------- bf16 MFMA GEMM: C[m,n] = sum_k A[m,k] * W[n,k] ------------
// A (M x K) bf16 row-major, W (Nact x K) bf16 row-major. 128x64 tile, 4 waves.
// Fragment layout (16x16x32 bf16): operand elem j of lane l -> m(or n)=l&15,
// k=(l>>4)*8+j  => one contiguous short8 per lane. D: col=l&15, row=(l>>4)*4+r.
// EPI==0: out0[m*Nact+n].  EPI==1 (in_proj split): n<192 -> out0 else out1.
template <int EPI>
__global__ __launch_bounds__(256) void k_mgemm(const short* __restrict__ A,
                                               const short* __restrict__ Wb,
                                               float* __restrict__ out0,
                                               float* __restrict__ out1,
                                               int Nact, int K) {
    const int m0 = blockIdx.x * 128;
    const int n0 = blockIdx.y * 64;
    const int wid = threadIdx.x >> 6;
    const int lane = threadIdx.x & 63;
    const int wm = wid >> 1, wn = wid & 1;        // wave tile: 64 x 32
    const int mrow = m0 + wm * 64 + (lane & 15);
    const int ncol = n0 + wn * 32 + (lane & 15);
    const int koff = (lane >> 4) * 8;

    f32x4 acc[4][2] = {};
    for (int k0 = 0; k0 < K; k0 += 32) {
        short8v af[4], bf[2];
#pragma unroll
        for (int mf = 0; mf < 4; mf++)
            af[mf] = *reinterpret_cast<const short8v*>(
                A + (size_t)(mrow + mf * 16) * K + k0 + koff);
#pragma unroll
        for (int nf = 0; nf < 2; nf++) {
            int r = ncol + nf * 16;
            short8v z = {0, 0, 0, 0, 0, 0, 0, 0};
            bf[nf] = (r < Nact)
                ? *reinterpret_cast<const short8v*>(Wb + (size_t)r * K + k0 + koff)
                : z;
        }
#pragma unroll
        for (int mf = 0; mf < 4; mf++)
#pragma unroll
            for (int nf = 0; nf < 2; nf++)
                acc[mf][nf] = __builtin_amdgcn_mfma_f32_16x16x32_bf16(
                    af[mf], bf[nf], acc[mf][nf], 0, 0, 0);
    }
    const int prow = (lane >> 4) * 4;
    const int pcol = lane & 15;
#pragma unroll
    for (int mf = 0; mf < 4; mf++) {
        int mbase = m0 + wm * 64 + mf * 16 + prow;
#pragma unroll
        for (int nf = 0; nf < 2; nf++) {
            int n = n0 + wn * 32 + nf * 16 + pcol;
#pragma unroll
            for (int r = 0; r < 4; r++) {
                int m = mbase + r;
                if (EPI == 0) {
                    if (n < Nact) out0[(size_t)m * Nact + n] = acc[mf][nf][r];
                } else {
                    if (n < 192) out0[(size_t)m * 192 + n] = acc[mf][nf][r];
                    else         out1[(size_t)m * 192 + (n - 192)] = acc[mf][nf][r];
                }
            }
        }
    }
}

// ---------------- depthwise 3x3 conv + bias + SiLU (emits f32 and bf16) -----
__global__ __launch_bounds__(256) void k_conv(const float* __restrict__ xf,
                                              const float* __restrict__ cw,
                                              const float* __restrict__ cb,
                                              float* __restrict__ xc,
                                              short* __restrict__ xc_bf) {
    size_t i = (size_t)blockIdx.x * 256 + threadIdx.x;  // over B*H*W*Dn
    int d = (int)(i % Dn);
    int p = (int)(i / Dn);
    int w = p & 63; p >>= 6;
    int h = p & 63; p >>= 6;
    int b = p;
    float acc = cb[d];
#pragma unroll
    for (int kh = 0; kh < 3; kh++) {
        int hh = h + kh - 1;
        if (hh < 0 || hh >= H_) continue;
#pragma unroll
        for (int kw = 0; kw < 3; kw++) {
            int ww = w + kw - 1;
            if (ww < 0 || ww >= W_) continue;
            acc = fmaf(xf[(((size_t)b * H_ + hh) * W_ + ww) * Dn + d],
                       cw[d * 9 + kh * 3 + kw], acc);
        }
    }
    float sig = 1.f / (1.f + __expf(-acc));
    float v = acc * sig;
    xc[i] = v;
    xc_bf[i] = f2bf(v);
}

// ---------------- scan phase 1: per-chunk (prod(a), h_partial) --------------
__global__ __launch_bounds__(192) void k_scan1(const float* __restrict__ xc,
                                               const float* __restrict__ xdbl,
                                               const float* __restrict__ dtw_all,
                                               const float* __restrict__ dtb_all,
                                               const float* __restrict__ alog,
                                               float* __restrict__ Aprod,
                                               float* __restrict__ hpart) {
    const int blk = blockIdx.x;            // ((b*K + k)*NC + c)
    const int c = blk % NC;
    const int k = (blk / NC) % K_;
    const int b = blk / (NC * K_);
    const int d = threadIdx.x;
    const int t0 = c * CS;

    __shared__ float sx[CS][CPROJ];        // dt_r(12) | B(8) | C(8) per step
    for (int i = d; i < CS * CPROJ; i += 192) {
        int ts = i / CPROJ, j = i % CPROJ;
        sx[ts][j] = xdbl[((size_t)b * L_ + map_t(k, t0 + ts)) * (K_ * CPROJ) + k * CPROJ + j];
    }
    __syncthreads();

    float dtw[R_];
#pragma unroll
    for (int r = 0; r < R_; r++) dtw[r] = dtw_all[((size_t)k * Dn + d) * R_ + r];
    const float bias = dtb_all[k * Dn + d];
    float Av[Nst];
#pragma unroll
    for (int n = 0; n < Nst; n++) Av[n] = -__expf(alog[((size_t)k * Dn + d) * Nst + n]);

    float h[Nst] = {}, Ap[Nst];
#pragma unroll
    for (int n = 0; n < Nst; n++) Ap[n] = 1.f;

    float u_next = xc[((size_t)b * L_ + map_t(k, t0)) * Dn + d];
    for (int ts = 0; ts < CS; ts++) {
        float u = u_next;
        if (ts + 1 < CS) u_next = xc[((size_t)b * L_ + map_t(k, t0 + ts + 1)) * Dn + d];
        float x = bias;
#pragma unroll
        for (int r = 0; r < R_; r++) x = fmaf(sx[ts][r], dtw[r], x);
        float delta = softplus_f(x);
        float du = delta * u;
#pragma unroll
        for (int n = 0; n < Nst; n++) {
            float a = __expf(delta * Av[n]);
            Ap[n] *= a;
            h[n] = fmaf(a, h[n], du * sx[ts][R_ + n]);
        }
    }
    size_t base = ((((size_t)(b * K_ + k) * NC + c) * Dn + d)) * Nst;
#pragma unroll
    for (int n = 0; n < Nst; n++) { Aprod[base + n] = Ap[n]; hpart[base + n] = h[n]; }
}

// ---------------- scan phase 2: chunk-level recurrence -----------------------
__global__ __launch_bounds__(256) void k_scan2(const float* __restrict__ Aprod,
                                               const float* __restrict__ hpart,
                                               float* __restrict__ hin) {
    int idx = blockIdx.x * 256 + threadIdx.x;   // B*K*Dn*Nst = 49152 exactly
    int dn = idx % (Dn * Nst);
    int bk = idx / (Dn * Nst);
    size_t stride = (size_t)Dn * Nst;
    size_t base = (size_t)bk * NC * stride + dn;
    float h = 0.f;
    for (int cc = 0; cc < NC; cc++) {
        size_t s = base + (size_t)cc * stride;
        hin[s] = h;
        h = fmaf(Aprod[s], h, hpart[s]);
    }
}

// ---------------- scan phase 3: recompute with h_in, emit y (scatter) -------
__global__ __launch_bounds__(192) void k_scan3(const float* __restrict__ xc,
                                               const float* __restrict__ xdbl,
                                               const float* __restrict__ dtw_all,
                                               const float* __restrict__ dtb_all,
                                               const float* __restrict__ alog,
                                               const float* __restrict__ dvec,
                                               const float* __restrict__ hin,
                                               float* __restrict__ ycomb) {
    const int blk = blockIdx.x;
    const int c = blk % NC;
    const int k = (blk / NC) % K_;
    const int b = blk / (NC * K_);
    const int d = threadIdx.x;
    const int t0 = c * CS;

    __shared__ float sx[CS][CPROJ];
    for (int i = d; i < CS * CPROJ; i += 192) {
        int ts = i / CPROJ, j = i % CPROJ;
        sx[ts][j] = xdbl[((size_t)b * L_ + map_t(k, t0 + ts)) * (K_ * CPROJ) + k * CPROJ + j];
    }
    __syncthreads();

    float dtw[R_];
#pragma unroll
    for (int r = 0; r < R_; r++) dtw[r] = dtw_all[((size_t)k * Dn + d) * R_ + r];
    const float bias = dtb_all[k * Dn + d];
    const float Dk = dvec[k * Dn + d];
    float Av[Nst];
#pragma unroll
    for (int n = 0; n < Nst; n++) Av[n] = -__expf(alog[((size_t)k * Dn + d) * Nst + n]);

    size_t base = ((((size_t)(b * K_ + k) * NC + c) * Dn + d)) * Nst;
    float h[Nst];
#pragma unroll
    for (int n = 0; n < Nst; n++) h[n] = hin[base + n];

    int lm = map_t(k, t0);
    float u_next = xc[((size_t)b * L_ + lm) * Dn + d];
    for (int ts = 0; ts < CS; ts++) {
        int lm_cur = lm;
        float u = u_next;
        if (ts + 1 < CS) {
            lm = map_t(k, t0 + ts + 1);
            u_next = xc[((size_t)b * L_ + lm) * Dn + d];
        }
        float x = bias;
#pragma unroll
        for (int r = 0; r < R_; r++) x = fmaf(sx[ts][r], dtw[r], x);
        float delta = softplus_f(x);
        float du = delta * u;
        float y = 0.f;
#pragma unroll
        for (int n = 0; n < Nst; n++) {
            float a = __expf(delta * Av[n]);
            h[n] = fmaf(a, h[n], du * sx[ts][R_ + n]);
            y = fmaf(h[n], sx[ts][R_ + Nst + n], y);
        }
        float outv = fmaf(Dk, u, y);
        atomicAdd(&ycomb[((size_t)b * L_ + lm_cur) * Dn + d], outv);
    }
}

// ---------------- combine output: LayerNorm(Dn) * SiLU(z), emit bf16 --------
__global__ __launch_bounds__(192) void k_ln(const float* __restrict__ ycomb,
                                            const float* __restrict__ zbuf,
                                            const float* __restrict__ lnw,
                                            const float* __restrict__ lnb,
                                            short* __restrict__ yfin_bf) {
    const int bl = blockIdx.x;     // b*L + l
    const int d = threadIdx.x;
    float v = ycomb[(size_t)bl * Dn + d];
    float s = v, s2 = v * v;
#pragma unroll
    for (int o = 32; o > 0; o >>= 1) {
        s += __shfl_down(s, o);
        s2 += __shfl_down(s2, o);
    }
    __shared__ float red[6];
    int wv = d >> 6;
    if ((d & 63) == 0) { red[wv] = s; red[3 + wv] = s2; }
    __syncthreads();
    float sum = red[0] + red[1] + red[2];
    float sum2 = red[3] + red[4] + red[5];
    const float inv = 1.f / 192.f;
    float mu = sum * inv;
    float var = sum2 * inv - mu * mu;
    float rstd = rsqrtf(var + 1e-5f);
    float zz = zbuf[(size_t)bl * Dn + d];
    float sig = 1.f / (1.f + __expf(-zz));
    float res = ((v - mu) * rstd * lnw[d] + lnb[d]) * (zz * sig);
    yfin_bf[(size_t)bl * Dn + d] = f2bf(res);
}

// ---------------- launcher ---------------------------------------------------
extern "C" void kernel_launch(void* const* d_in, const int* in_sizes, int n_in,
                              void* d_out, int out_size, void* d_ws, size_t ws_size,
                              hipStream_t stream) {
    const float* x    = (const float*)d_in[0];
    const float* w_in = (const float*)d_in[1];
    const float* cw   = (const float*)d_in[2];
    const float* cb   = (const float*)d_in[3];
    const float* xpw  = (const float*)d_in[4];   // (K,28,192) == (112,192)
    const float* dtw  = (const float*)d_in[5];
    const float* dtb  = (const float*)d_in[6];
    const float* alog = (const float*)d_in[7];
    const float* dvec = (const float*)d_in[8];
    const float* lnw  = (const float*)d_in[9];
    const float* lnb  = (const float*)d_in[10];
    const float* wout = (const float*)d_in[11];
    float* out = (float*)d_out;

    float* ws = (float*)d_ws;
    const size_t MBL = (size_t)MROWS * Dn;               // 6,291,456
    const size_t SCN = (size_t)B_ * K_ * NC * Dn * Nst;  // 3,145,728

    float* xc    = ws;                        // f32 conv out (scan input u)
    float* z     = xc + MBL;                  // gate
    float* xdbl  = z + MBL;                   // (B*L, 112) f32
    float* Aprod = xdbl + (size_t)MROWS * (K_ * CPROJ);
    float* hpart = Aprod + SCN;
    float* hin   = hpart + SCN;
    float* ycomb = hin + SCN;                 // (B*L, Dn) scatter accum
    float* xf    = ycomb + MBL;               // conv input; dead after conv
    short* xc_bf = (short*)(xf + MBL);        // bf16 copy of xc (MBL shorts)
    short* w_bf  = xc_bf + MBL;               // 132096 shorts
    // aliases (lifetimes verified): x_bf dead after in_proj -> lives in ycomb
    // (memset of ycomb happens AFTER in_proj); yfin_bf lives in xdbl region
    // (xdbl dead after scan3, k_ln runs after scan3).
    short* x_bf    = (short*)ycomb;
    short* yfin_bf = (short*)xdbl;

    // 0. convert inputs to bf16
    k_cvt_x<<<(int)(MBL / (256 * 8)), 256, 0, stream>>>(x, x_bf);
    k_cvt_w<<<(WTOTAL / 8 + 255) / 256, 256, 0, stream>>>(w_in, xpw, wout, w_bf);
    // 1. in_proj (MFMA): xz = x @ W^T, split -> xf, z
    k_mgemm<1><<<dim3(MROWS / 128, 6), 256, 0, stream>>>(x_bf, w_bf + WOFF_IN,
                                                         xf, z, 2 * Dn, C_);
    // zero the scatter accumulator (after in_proj: x_bf alias released)
    hipMemsetAsync(ycomb, 0, MBL * sizeof(float), stream);
    // 2. depthwise conv 3x3 + bias + SiLU (f32 + bf16 outputs)
    k_conv<<<(int)(MBL / 256), 256, 0, stream>>>(xf, cw, cb, xc, xc_bf);
    // 3. x_dbl for all 4 directions in one MFMA GEMM
    k_mgemm<0><<<dim3(MROWS / 128, 2), 256, 0, stream>>>(xc_bf, w_bf + WOFF_XP,
                                                         xdbl, nullptr,
                                                         K_ * CPROJ, Dn);
    // 4-6. chunked parallel selective scan
    k_scan1<<<B_ * K_ * NC, 192, 0, stream>>>(xc, xdbl, dtw, dtb, alog, Aprod, hpart);
    k_scan2<<<(B_ * K_ * Dn * Nst) / 256, 256, 0, stream>>>(Aprod, hpart, hin);
    k_scan3<<<B_ * K_ * NC, 192, 0, stream>>>(xc, xdbl, dtw, dtb, alog, dvec, hin, ycomb);
    // 7. LayerNorm * SiLU(z) -> bf16
    k_ln<<<MROWS, 192, 0, stream>>>(ycomb, z, lnw, lnb, yfin_bf);
    // 8. out_proj (MFMA) -> d_out (f32)
    k_mgemm<0><<<dim3(MROWS / 128, 3), 256, 0, stream>>>(yfin_bf, w_bf + WOFF_OUT,
                                                         out, nullptr, C_, Dn);
}

// Round 3
// 251.033 us; speedup vs baseline: 1.5868x; 1.2285x over previous
//
#include <hip/hip_runtime.h>
#include <hip/hip_bf16.h>

// ---------------- problem constants (fixed by setup_inputs) ----------------
constexpr int B_  = 8;
constexpr int H_  = 64;
constexpr int W_  = 64;
constexpr int C_  = 192;
constexpr int Dn  = 192;
constexpr int Nst = 8;    // state dim N
constexpr int R_  = 12;
constexpr int K_  = 4;    // directions
constexpr int L_  = H_ * W_;          // 4096
constexpr int CS  = 64;               // scan chunk size
constexpr int NC  = L_ / CS;          // 64 chunks
constexpr int CPROJ = R_ + 2 * Nst;   // 28 proj outputs per direction
constexpr int MROWS = B_ * L_;        // 32768

typedef __attribute__((ext_vector_type(8))) short short8v;
typedef __attribute__((ext_vector_type(4))) float f32x4;

// t -> spatial position for direction k (verified round 0)
__device__ __forceinline__ int map_t(int k, int t) {
    int tt = (k >= 2) ? (L_ - 1 - t) : t;
    if (k & 1) tt = (tt & 63) * 64 + (tt >> 6);
    return tt;
}

__device__ __forceinline__ short f2bf(float f) {   // round-to-nearest-even
    unsigned u = __float_as_uint(f);
    u += 0x7FFFu + ((u >> 16) & 1u);
    return (short)(u >> 16);
}
__device__ __forceinline__ float bf2f(short s) {
    return __uint_as_float(((unsigned)(unsigned short)s) << 16);
}

// ---------------- f32 -> bf16 converters ------------------------------------
__global__ __launch_bounds__(256) void k_cvt_x(const float* __restrict__ in,
                                               short* __restrict__ out) {
    size_t i = ((size_t)blockIdx.x * 256 + threadIdx.x) * 8;
    float4 a = *reinterpret_cast<const float4*>(in + i);
    float4 b = *reinterpret_cast<const float4*>(in + i + 4);
    short8v v = {f2bf(a.x), f2bf(a.y), f2bf(a.z), f2bf(a.w),
                 f2bf(b.x), f2bf(b.y), f2bf(b.z), f2bf(b.w)};
    *reinterpret_cast<short8v*>(out + i) = v;
}

constexpr int WOFF_IN  = 0;               // w_in  (384x192)
constexpr int WOFF_XP  = 73728;           // xpw   (112x192)
constexpr int WOFF_OUT = 95232;           // wout  (192x192)
constexpr int WTOTAL   = 132096;
__global__ __launch_bounds__(256) void k_cvt_w(const float* __restrict__ w_in,
                                               const float* __restrict__ xpw,
                                               const float* __restrict__ wout,
                                               short* __restrict__ dst) {
    int base = (blockIdx.x * 256 + threadIdx.x) * 8;
    if (base >= WTOTAL) return;
    const float* src; int off;
    if (base < WOFF_XP)       { src = w_in; off = base; }
    else if (base < WOFF_OUT) { src = xpw;  off = base - WOFF_XP; }
    else                      { src = wout; off = base - WOFF_OUT; }
    float4 a = *reinterpret_cast<const float4*>(src + off);
    float4 b = *reinterpret_cast<const float4*>(src + off + 4);
    short8v v = {f2bf(a.x), f2bf(a.y), f2bf(a.z), f2bf(a.w),
                 f2bf(b.x), f2bf(b.y), f2bf(b.z), f2bf(b.w)};
    *reinterpret_cast<short8v*>(dst + base) = v;
}

// ---------------- bf16 MFMA GEMM cores --------------------------------------
// A (M x K) bf16 row-major, W (Nact x K) bf16 row-major. 128x64 tile, 4 waves.
// 16x16x32 frag: operand elem j of lane l -> row=l&15, k=(l>>4)*8+j (one
// contiguous short8). D: col=l&15, row=(l>>4)*4+r.
__device__ __forceinline__ void mgemm_core(const short* __restrict__ A,
                                           const short* __restrict__ Wb,
                                           f32x4 (&acc)[4][2],
                                           int mrow, int ncol, int Nact, int K) {
    const int lane = threadIdx.x & 63;
    const int koff = (lane >> 4) * 8;
    for (int k0 = 0; k0 < K; k0 += 32) {
        short8v af[4], bfr[2];
#pragma unroll
        for (int mf = 0; mf < 4; mf++)
            af[mf] = *reinterpret_cast<const short8v*>(
                A + (size_t)(mrow + mf * 16) * K + k0 + koff);
#pragma unroll
        for (int nf = 0; nf < 2; nf++) {
            int r = ncol + nf * 16;
            short8v z = {0, 0, 0, 0, 0, 0, 0, 0};
            bfr[nf] = (r < Nact)
                ? *reinterpret_cast<const short8v*>(Wb + (size_t)r * K + k0 + koff)
                : z;
        }
#pragma unroll
        for (int mf = 0; mf < 4; mf++)
#pragma unroll
            for (int nf = 0; nf < 2; nf++)
                acc[mf][nf] = __builtin_amdgcn_mfma_f32_16x16x32_bf16(
                    af[mf], bfr[nf], acc[mf][nf], 0, 0, 0);
    }
}

// f32-output GEMM (x_proj, out_proj)
__global__ __launch_bounds__(256) void k_mgemm_f(const short* __restrict__ A,
                                                 const short* __restrict__ Wb,
                                                 float* __restrict__ out0,
                                                 int Nact, int K) {
    const int m0 = blockIdx.x * 128, n0 = blockIdx.y * 64;
    const int wid = threadIdx.x >> 6, lane = threadIdx.x & 63;
    const int wm = wid >> 1, wn = wid & 1;
    f32x4 acc[4][2] = {};
    mgemm_core(A, Wb, acc, m0 + wm * 64 + (lane & 15), n0 + wn * 32 + (lane & 15),
               Nact, K);
    const int prow = (lane >> 4) * 4, pcol = lane & 15;
#pragma unroll
    for (int mf = 0; mf < 4; mf++) {
        int mbase = m0 + wm * 64 + mf * 16 + prow;
#pragma unroll
        for (int nf = 0; nf < 2; nf++) {
            int n = n0 + wn * 32 + nf * 16 + pcol;
            if (n >= Nact) continue;
#pragma unroll
            for (int r = 0; r < 4; r++)
                out0[(size_t)(mbase + r) * Nact + n] = acc[mf][nf][r];
        }
    }
}

// in_proj: split bf16 outputs (xf | z), each ldc=192
__global__ __launch_bounds__(256) void k_mgemm_in(const short* __restrict__ A,
                                                  const short* __restrict__ Wb,
                                                  short* __restrict__ xf_bf,
                                                  short* __restrict__ z_bf,
                                                  int K) {
    const int m0 = blockIdx.x * 128, n0 = blockIdx.y * 64;
    const int wid = threadIdx.x >> 6, lane = threadIdx.x & 63;
    const int wm = wid >> 1, wn = wid & 1;
    f32x4 acc[4][2] = {};
    mgemm_core(A, Wb, acc, m0 + wm * 64 + (lane & 15), n0 + wn * 32 + (lane & 15),
               384, K);
    const int prow = (lane >> 4) * 4, pcol = lane & 15;
#pragma unroll
    for (int mf = 0; mf < 4; mf++) {
        int mbase = m0 + wm * 64 + mf * 16 + prow;
#pragma unroll
        for (int nf = 0; nf < 2; nf++) {
            int n = n0 + wn * 32 + nf * 16 + pcol;
#pragma unroll
            for (int r = 0; r < 4; r++) {
                int m = mbase + r;
                if (n < 192) xf_bf[(size_t)m * 192 + n] = f2bf(acc[mf][nf][r]);
                else         z_bf[(size_t)m * 192 + (n - 192)] = f2bf(acc[mf][nf][r]);
            }
        }
    }
}

// ---------------- depthwise 3x3 conv + bias + SiLU (bf16 in/out) ------------
__global__ __launch_bounds__(256) void k_conv(const short* __restrict__ xfb,
                                              const float* __restrict__ cw,
                                              const float* __restrict__ cb,
                                              short* __restrict__ xcb) {
    size_t i = (size_t)blockIdx.x * 256 + threadIdx.x;  // over B*H*W*Dn
    int d = (int)(i % Dn);
    int p = (int)(i / Dn);
    int w = p & 63; p >>= 6;
    int h = p & 63; p >>= 6;
    int b = p;
    float acc = cb[d];
#pragma unroll
    for (int kh = 0; kh < 3; kh++) {
        int hh = h + kh - 1;
        if (hh < 0 || hh >= H_) continue;
#pragma unroll
        for (int kw = 0; kw < 3; kw++) {
            int ww = w + kw - 1;
            if (ww < 0 || ww >= W_) continue;
            acc = fmaf(bf2f(xfb[(((size_t)b * H_ + hh) * W_ + ww) * Dn + d]),
                       cw[d * 9 + kh * 3 + kw], acc);
        }
    }
    float sig = 1.f / (1.f + __expf(-acc));
    xcb[i] = f2bf(acc * sig);
}

// ---------------- per-step delta / e1 helper --------------------------------
// x = dt pre-activation. delta = softplus(x); e1 = exp(-delta) = 1/(1+e^x).
__device__ __forceinline__ void delta_e1(float x, float& delta, float& e1) {
    if (x > 20.f) { delta = x; e1 = __expf(-x); }
    else {
        float t = __expf(x);
        delta = __logf(1.f + t);
        e1 = __builtin_amdgcn_rcpf(1.f + t);
    }
}

// ---------------- scan phase 1: per-chunk (prod(a), h_partial) --------------
__global__ __launch_bounds__(192) void k_scan1(const short* __restrict__ xcb,
                                               const float* __restrict__ xdbl,
                                               const float* __restrict__ dtw_all,
                                               const float* __restrict__ dtb_all,
                                               const float* __restrict__ alog,
                                               float* __restrict__ Aprod,
                                               float* __restrict__ hpart) {
    const int blk = blockIdx.x;            // ((b*K + k)*NC + c)
    const int c = blk % NC;
    const int k = (blk / NC) % K_;
    const int b = blk / (NC * K_);
    const int d = threadIdx.x;
    const int t0 = c * CS;

    __shared__ float sx[CS][CPROJ];        // dt_r(12) | B(8) | C(8)
    for (int i = d; i < CS * CPROJ; i += 192) {
        int ts = i / CPROJ, j = i % CPROJ;
        sx[ts][j] = xdbl[((size_t)b * L_ + map_t(k, t0 + ts)) * (K_ * CPROJ) + k * CPROJ + j];
    }
    __syncthreads();

    float dtw[R_];
#pragma unroll
    for (int r = 0; r < R_; r++) dtw[r] = dtw_all[((size_t)k * Dn + d) * R_ + r];
    const float bias = dtb_all[k * Dn + d];
    float Av[Nst];
    bool fast = true;
#pragma unroll
    for (int n = 0; n < Nst; n++) {
        Av[n] = -__expf(alog[((size_t)k * Dn + d) * Nst + n]);
        fast = fast && (fabsf(Av[n] + (float)(n + 1)) < 1e-3f);
    }

    float h[Nst] = {};
    float Ap[Nst];
#pragma unroll
    for (int n = 0; n < Nst; n++) Ap[n] = 1.f;
    float e1p = 1.f;

    float u_next = bf2f(xcb[((size_t)b * L_ + map_t(k, t0)) * Dn + d]);
    if (fast) {
        for (int ts = 0; ts < CS; ts++) {
            float u = u_next;
            if (ts + 1 < CS) u_next = bf2f(xcb[((size_t)b * L_ + map_t(k, t0 + ts + 1)) * Dn + d]);
            float x = bias;
#pragma unroll
            for (int r = 0; r < R_; r++) x = fmaf(sx[ts][r], dtw[r], x);
            float delta, e1; delta_e1(x, delta, e1);
            float du = delta * u;
            e1p *= e1;
            float a2 = e1 * e1, a3 = a2 * e1, a4 = a2 * a2;
            float a5 = a4 * e1, a6 = a4 * a2, a7 = a4 * a3, a8 = a4 * a4;
            float a[Nst] = {e1, a2, a3, a4, a5, a6, a7, a8};
#pragma unroll
            for (int n = 0; n < Nst; n++)
                h[n] = fmaf(a[n], h[n], du * sx[ts][R_ + n]);
        }
        float p2 = e1p * e1p, p3 = p2 * e1p, p4 = p2 * p2;
        Ap[0] = e1p; Ap[1] = p2; Ap[2] = p3; Ap[3] = p4;
        Ap[4] = p4 * e1p; Ap[5] = p4 * p2; Ap[6] = p4 * p3; Ap[7] = p4 * p4;
    } else {
        for (int ts = 0; ts < CS; ts++) {
            float u = u_next;
            if (ts + 1 < CS) u_next = bf2f(xcb[((size_t)b * L_ + map_t(k, t0 + ts + 1)) * Dn + d]);
            float x = bias;
#pragma unroll
            for (int r = 0; r < R_; r++) x = fmaf(sx[ts][r], dtw[r], x);
            float delta, e1; delta_e1(x, delta, e1);
            float du = delta * u;
#pragma unroll
            for (int n = 0; n < Nst; n++) {
                float a = __expf(delta * Av[n]);
                Ap[n] *= a;
                h[n] = fmaf(a, h[n], du * sx[ts][R_ + n]);
            }
        }
    }
    size_t base = ((((size_t)(b * K_ + k) * NC + c) * Dn + d)) * Nst;
#pragma unroll
    for (int n = 0; n < Nst; n++) { Aprod[base + n] = Ap[n]; hpart[base + n] = h[n]; }
}

// ---------------- scan phase 2: chunk-level recurrence -----------------------
__global__ __launch_bounds__(256) void k_scan2(const float* __restrict__ Aprod,
                                               const float* __restrict__ hpart,
                                               float* __restrict__ hin) {
    int idx = blockIdx.x * 256 + threadIdx.x;   // B*K*Dn*Nst = 49152
    int dn = idx % (Dn * Nst);
    int bk = idx / (Dn * Nst);
    size_t stride = (size_t)Dn * Nst;
    size_t base = (size_t)bk * NC * stride + dn;
    float h = 0.f;
    for (int cc = 0; cc < NC; cc++) {
        size_t s = base + (size_t)cc * stride;
        hin[s] = h;
        h = fmaf(Aprod[s], h, hpart[s]);
    }
}

// ---------------- scan phase 3: recompute with h_in, emit y (plain store) ---
__global__ __launch_bounds__(192) void k_scan3(const short* __restrict__ xcb,
                                               const float* __restrict__ xdbl,
                                               const float* __restrict__ dtw_all,
                                               const float* __restrict__ dtb_all,
                                               const float* __restrict__ alog,
                                               const float* __restrict__ dvec,
                                               const float* __restrict__ hin,
                                               short* __restrict__ y0,
                                               short* __restrict__ y1,
                                               short* __restrict__ y2,
                                               short* __restrict__ y3) {
    const int blk = blockIdx.x;
    const int c = blk % NC;
    const int k = (blk / NC) % K_;
    const int b = blk / (NC * K_);
    const int d = threadIdx.x;
    const int t0 = c * CS;
    short* __restrict__ yk = (k == 0) ? y0 : (k == 1) ? y1 : (k == 2) ? y2 : y3;

    __shared__ float sx[CS][CPROJ];
    for (int i = d; i < CS * CPROJ; i += 192) {
        int ts = i / CPROJ, j = i % CPROJ;
        sx[ts][j] = xdbl[((size_t)b * L_ + map_t(k, t0 + ts)) * (K_ * CPROJ) + k * CPROJ + j];
    }
    __syncthreads();

    float dtw[R_];
#pragma unroll
    for (int r = 0; r < R_; r++) dtw[r] = dtw_all[((size_t)k * Dn + d) * R_ + r];
    const float bias = dtb_all[k * Dn + d];
    const float Dk = dvec[k * Dn + d];
    float Av[Nst];
    bool fast = true;
#pragma unroll
    for (int n = 0; n < Nst; n++) {
        Av[n] = -__expf(alog[((size_t)k * Dn + d) * Nst + n]);
        fast = fast && (fabsf(Av[n] + (float)(n + 1)) < 1e-3f);
    }

    size_t hbase = ((((size_t)(b * K_ + k) * NC + c) * Dn + d)) * Nst;
    float h[Nst];
#pragma unroll
    for (int n = 0; n < Nst; n++) h[n] = hin[hbase + n];

    int lm = map_t(k, t0);
    float u_next = bf2f(xcb[((size_t)b * L_ + lm) * Dn + d]);
    if (fast) {
        for (int ts = 0; ts < CS; ts++) {
            int lm_cur = lm;
            float u = u_next;
            if (ts + 1 < CS) {
                lm = map_t(k, t0 + ts + 1);
                u_next = bf2f(xcb[((size_t)b * L_ + lm) * Dn + d]);
            }
            float x = bias;
#pragma unroll
            for (int r = 0; r < R_; r++) x = fmaf(sx[ts][r], dtw[r], x);
            float delta, e1; delta_e1(x, delta, e1);
            float du = delta * u;
            float a2 = e1 * e1, a3 = a2 * e1, a4 = a2 * a2;
            float a5 = a4 * e1, a6 = a4 * a2, a7 = a4 * a3, a8 = a4 * a4;
            float a[Nst] = {e1, a2, a3, a4, a5, a6, a7, a8};
            float y = 0.f;
#pragma unroll
            for (int n = 0; n < Nst; n++) {
                h[n] = fmaf(a[n], h[n], du * sx[ts][R_ + n]);
                y = fmaf(h[n], sx[ts][R_ + Nst + n], y);
            }
            yk[((size_t)b * L_ + lm_cur) * Dn + d] = f2bf(fmaf(Dk, u, y));
        }
    } else {
        for (int ts = 0; ts < CS; ts++) {
            int lm_cur = lm;
            float u = u_next;
            if (ts + 1 < CS) {
                lm = map_t(k, t0 + ts + 1);
                u_next = bf2f(xcb[((size_t)b * L_ + lm) * Dn + d]);
            }
            float x = bias;
#pragma unroll
            for (int r = 0; r < R_; r++) x = fmaf(sx[ts][r], dtw[r], x);
            float delta, e1; delta_e1(x, delta, e1);
            float du = delta * u;
            float y = 0.f;
#pragma unroll
            for (int n = 0; n < Nst; n++) {
                float a = __expf(delta * Av[n]);
                h[n] = fmaf(a, h[n], du * sx[ts][R_ + n]);
                y = fmaf(h[n], sx[ts][R_ + Nst + n], y);
            }
            yk[((size_t)b * L_ + lm_cur) * Dn + d] = f2bf(fmaf(Dk, u, y));
        }
    }
}

// ---------------- merge 4 dirs + LayerNorm(Dn) * SiLU(z) -> bf16 ------------
// one wave per row; block = 4 waves = 4 rows
__global__ __launch_bounds__(256) void k_ln(const short* __restrict__ y0,
                                            const short* __restrict__ y1,
                                            const short* __restrict__ y2,
                                            const short* __restrict__ y3,
                                            const short* __restrict__ zb,
                                            const float* __restrict__ lnw,
                                            const float* __restrict__ lnb,
                                            short* __restrict__ yfin) {
    const int row = blockIdx.x * 4 + (threadIdx.x >> 6);
    const int lane = threadIdx.x & 63;
    const size_t base = (size_t)row * Dn;
    float v[3];
    float s = 0.f, s2 = 0.f;
#pragma unroll
    for (int j = 0; j < 3; j++) {
        size_t idx = base + lane + j * 64;
        v[j] = bf2f(y0[idx]) + bf2f(y1[idx]) + bf2f(y2[idx]) + bf2f(y3[idx]);
        s += v[j];
        s2 = fmaf(v[j], v[j], s2);
    }
#pragma unroll
    for (int o = 1; o < 64; o <<= 1) {
        s += __shfl_xor(s, o);
        s2 += __shfl_xor(s2, o);
    }
    const float inv = 1.f / 192.f;
    float mu = s * inv;
    float var = s2 * inv - mu * mu;
    float rstd = rsqrtf(var + 1e-5f);
#pragma unroll
    for (int j = 0; j < 3; j++) {
        int dd = lane + j * 64;
        size_t idx = base + dd;
        float zz = bf2f(zb[idx]);
        float sig = 1.f / (1.f + __expf(-zz));
        float res = ((v[j] - mu) * rstd * lnw[dd] + lnb[dd]) * (zz * sig);
        yfin[idx] = f2bf(res);
    }
}

// ---------------- launcher ---------------------------------------------------
extern "C" void kernel_launch(void* const* d_in, const int* in_sizes, int n_in,
                              void* d_out, int out_size, void* d_ws, size_t ws_size,
                              hipStream_t stream) {
    const float* x    = (const float*)d_in[0];
    const float* w_in = (const float*)d_in[1];
    const float* cw   = (const float*)d_in[2];
    const float* cb   = (const float*)d_in[3];
    const float* xpw  = (const float*)d_in[4];
    const float* dtw  = (const float*)d_in[5];
    const float* dtb  = (const float*)d_in[6];
    const float* alog = (const float*)d_in[7];
    const float* dvec = (const float*)d_in[8];
    const float* lnw  = (const float*)d_in[9];
    const float* lnb  = (const float*)d_in[10];
    const float* wout = (const float*)d_in[11];
    float* out = (float*)d_out;

    const size_t SH  = (size_t)MROWS * Dn;               // 6,291,456 elems
    const size_t SCN = (size_t)B_ * K_ * NC * Dn * Nst;  // 3,145,728 elems

    char* p = (char*)d_ws;
    short* x_bf  = (short*)p; p += SH * 2;               // region0 -> y0
    short* xf_bf = (short*)p; p += SH * 2;               // region1 -> y1
    short* z_bf  = (short*)p; p += SH * 2;               // region2
    short* xc_bf = (short*)p; p += SH * 2;               // region3
    float* xdbl  = (float*)p; p += (size_t)MROWS * (K_ * CPROJ) * 4;
    float* Aprod = (float*)p; p += SCN * 4;              // region5 -> y2
    float* hpart = (float*)p; p += SCN * 4;              // region6 -> y3
    float* hin   = (float*)p; p += SCN * 4;              // region7 -> yfin
    short* w_bf  = (short*)p;
    // aliases (lifetimes): y0<-x_bf (dead after in_proj), y1<-xf_bf (dead after
    // conv), y2<-Aprod, y3<-hpart (dead after scan2), yfin<-hin (dead after
    // scan3; k_ln runs after scan3).
    short* y0 = x_bf;
    short* y1 = xf_bf;
    short* y2 = (short*)Aprod;
    short* y3 = (short*)hpart;
    short* yfin_bf = (short*)hin;

    // 0. converts
    k_cvt_x<<<(int)(SH / (256 * 8)), 256, 0, stream>>>(x, x_bf);
    k_cvt_w<<<(WTOTAL / 8 + 255) / 256, 256, 0, stream>>>(w_in, xpw, wout, w_bf);
    // 1. in_proj (MFMA) -> xf_bf, z_bf
    k_mgemm_in<<<dim3(MROWS / 128, 6), 256, 0, stream>>>(x_bf, w_bf + WOFF_IN,
                                                         xf_bf, z_bf, C_);
    // 2. depthwise conv 3x3 + SiLU -> xc_bf
    k_conv<<<(int)(SH / 256), 256, 0, stream>>>(xf_bf, cw, cb, xc_bf);
    // 3. x_dbl (all 4 dirs, one MFMA GEMM) -> f32
    k_mgemm_f<<<dim3(MROWS / 128, 2), 256, 0, stream>>>(xc_bf, w_bf + WOFF_XP,
                                                        xdbl, K_ * CPROJ, Dn);
    // 4-6. chunked parallel selective scan
    k_scan1<<<B_ * K_ * NC, 192, 0, stream>>>(xc_bf, xdbl, dtw, dtb, alog, Aprod, hpart);
    k_scan2<<<(B_ * K_ * Dn * Nst) / 256, 256, 0, stream>>>(Aprod, hpart, hin);
    k_scan3<<<B_ * K_ * NC, 192, 0, stream>>>(xc_bf, xdbl, dtw, dtb, alog, dvec,
                                              hin, y0, y1, y2, y3);
    // 7. merge + LayerNorm * SiLU(z) -> bf16
    k_ln<<<MROWS / 4, 256, 0, stream>>>(y0, y1, y2, y3, z_bf, lnw, lnb, yfin_bf);
    // 8. out_proj (MFMA) -> d_out (f32)
    k_mgemm_f<<<dim3(MROWS / 128, 3), 256, 0, stream>>>(yfin_bf, w_bf + WOFF_OUT,
                                                        out, C_, Dn);
}